// Round 5
// baseline (894.709 us; speedup 1.0000x reference)
//
#include <hip/hip_runtime.h>
#include <math.h>

#define N 16384
#define D 23
#define K 16
#define NG 32               // cells per dim
#define NCELL (NG * NG * NG)
#define GINV 4.0f           // 1/cell width (cell = 0.25)
#define GOFF 4.0f           // domain [-4,4)

__device__ __forceinline__ int cellof(float v) {
  int b = (int)((v + GOFF) * GINV);
  return b < 0 ? 0 : (b > NG - 1 ? NG - 1 : b);
}

// Sorted ascending insert of (d2, jj) into register lists vald/vali (K deep).
// Safe for any d2 (no-op when d2 >= vald[K-1]).
#define TOPK_INSERT(vald, vali, d2v, jjv)                          \
  {                                                                \
    bool ck = (d2v) < vald[K - 1];                                 \
    _Pragma("unroll") for (int k = K - 1; k >= 0; --k) {           \
      bool ckm1 = (k > 0) ? ((d2v) < vald[k - 1]) : false;         \
      float nv = ckm1 ? vald[k - 1] : (ck ? (d2v) : vald[k]);      \
      int ni = ckm1 ? vali[k - 1] : (ck ? (jjv) : vali[k]);        \
      vald[k] = nv;                                                \
      vali[k] = ni;                                                \
      ck = ckm1;                                                   \
    }                                                              \
  }

// ---------------------------------------------------------------------------
// Kernel 0: zero hist + cnt2 (32768 ints each). grid 128 x 256.
// ---------------------------------------------------------------------------
__global__ __launch_bounds__(256) void zero_kernel(int* __restrict__ hist,
                                                   int* __restrict__ cnt2) {
  int i = blockIdx.x * 256 + threadIdx.x;
  hist[i] = 0;
  cnt2[i] = 0;
}

// ---------------------------------------------------------------------------
// Kernel 1: s = x@W_s + b_s, h = x@W_h + b_h; pack s4={sx,sy,sz,sq}, h4;
//           3-D cell histogram. Coalesced x via LDS staging.
// ---------------------------------------------------------------------------
__global__ __launch_bounds__(64) void prep_kernel(
    const float* __restrict__ x, const float* __restrict__ Ws,
    const float* __restrict__ bs, const float* __restrict__ Wh,
    const float* __restrict__ bh, float4* __restrict__ s4,
    float4* __restrict__ h4, int* __restrict__ hist) {
  __shared__ float lWs[D * 3], lWh[D * 3], lbs[3], lbh[3];
  __shared__ float xl[64 * D];
  for (int t = threadIdx.x; t < D * 3; t += 64) {
    lWs[t] = Ws[t];
    lWh[t] = Wh[t];
  }
  if (threadIdx.x < 3) {
    lbs[threadIdx.x] = bs[threadIdx.x];
    lbh[threadIdx.x] = bh[threadIdx.x];
  }
  const float* xb = x + (size_t)blockIdx.x * 64 * D;
  for (int j = threadIdx.x; j < 64 * D; j += 64) xl[j] = xb[j];
  __syncthreads();

  int i = blockIdx.x * 64 + threadIdx.x;
  float a0 = 0.f, a1 = 0.f, a2 = 0.f;
  float g0 = 0.f, g1 = 0.f, g2 = 0.f;
#pragma unroll
  for (int d = 0; d < D; ++d) {
    float xv = xl[threadIdx.x * D + d];
    a0 = fmaf(xv, lWs[d * 3 + 0], a0);
    a1 = fmaf(xv, lWs[d * 3 + 1], a1);
    a2 = fmaf(xv, lWs[d * 3 + 2], a2);
    g0 = fmaf(xv, lWh[d * 3 + 0], g0);
    g1 = fmaf(xv, lWh[d * 3 + 1], g1);
    g2 = fmaf(xv, lWh[d * 3 + 2], g2);
  }
  float s0 = __fadd_rn(a0, lbs[0]);
  float s1 = __fadd_rn(a1, lbs[1]);
  float s2 = __fadd_rn(a2, lbs[2]);
  float sq = fmaf(s2, s2, fmaf(s1, s1, __fmul_rn(s0, s0)));
  s4[i] = make_float4(s0, s1, s2, sq);
  h4[i] = make_float4(__fadd_rn(g0, lbh[0]), __fadd_rn(g1, lbh[1]),
                      __fadd_rn(g2, lbh[2]), 0.f);
  int cid = (cellof(s2) << 10) | (cellof(s1) << 5) | cellof(s0);
  atomicAdd(&hist[cid], 1);
}

// ---------------------------------------------------------------------------
// Kernel 2: exclusive prefix sum of hist[32768] -> offs[32769]. One block,
// 1024 threads x 32 elems.
// ---------------------------------------------------------------------------
__global__ __launch_bounds__(1024) void scan_kernel(const int* __restrict__ hist,
                                                    int* __restrict__ offs) {
  __shared__ int wsum[16];
  int t = threadIdx.x;
  int loc[32];
  int s = 0;
#pragma unroll
  for (int j = 0; j < 32; ++j) {
    loc[j] = hist[t * 32 + j];
    s += loc[j];
  }
  int lane = t & 63, wid = t >> 6;
  int v = s;
#pragma unroll
  for (int off = 1; off < 64; off <<= 1) {
    int o = __shfl_up(v, off);
    if (lane >= off) v += o;
  }
  if (lane == 63) wsum[wid] = v;
  __syncthreads();
  if (t == 0) {
    int acc = 0;
#pragma unroll
    for (int w = 0; w < 16; ++w) {
      int tmp = wsum[w];
      wsum[w] = acc;
      acc += tmp;
    }
  }
  __syncthreads();
  int run = wsum[wid] + (v - s);  // global exclusive prefix
#pragma unroll
  for (int j = 0; j < 32; ++j) {
    offs[t * 32 + j] = run;
    run += loc[j];
  }
  if (t == 1023) offs[NCELL] = run;  // == N
}

// ---------------------------------------------------------------------------
// Kernel 3: scatter into cell-sorted layout (+ sorted h, orig index)
// ---------------------------------------------------------------------------
__global__ __launch_bounds__(64) void scatter_kernel(
    const float4* __restrict__ s4, const float4* __restrict__ h4,
    const int* __restrict__ offs, int* __restrict__ cnt2,
    float4* __restrict__ s4s, float4* __restrict__ h4s,
    int* __restrict__ idxs) {
  int i = blockIdx.x * 64 + threadIdx.x;
  float4 s = s4[i];
  int cid = (cellof(s.z) << 10) | (cellof(s.y) << 5) | cellof(s.x);
  int pos = offs[cid] + atomicAdd(&cnt2[cid], 1);
  s4s[pos] = s;
  h4s[pos] = h4[i];
  idxs[pos] = i;
}

// ---------------------------------------------------------------------------
// Kernel 4: kNN + aggregate. One query per 16-lane group (4/wave, 16/block).
// Window = all cells intersecting ball(s_q, r); each (cz,cy) row is one
// contiguous run. Gate inserts on d2 <= r^2 (exact when cnt>=16, else retry
// with r*=1.6; it=7 falls back to full grid). Per-lane top-16 (exact), then
// 16-round in-group argmin extraction; rank e lands on lane e; aggregation
// is lane-parallel with shfl reduce.
// ---------------------------------------------------------------------------
__global__ __launch_bounds__(256) void knn_kernel(
    const float4* __restrict__ s4s, const float4* __restrict__ h4s,
    const int* __restrict__ idxs, const int* __restrict__ offs,
    float* __restrict__ aggr) {
  int glane = threadIdx.x & 15;
  int P = blockIdx.x * 16 + (threadIdx.x >> 4);  // sorted query position
  float4 si = s4s[P];
  float sqi = si.w;
  // Gaussian 16-NN radius estimate * 1.25 safety
  float r = 0.1925f * __expf(sqi * 0.16666667f);

  float vd[K];
  int vi[K];
  bool gdone = false;

  for (int it = 0; it < 8; ++it) {
    if (__all(gdone)) break;
    if (!gdone) {
      float r2;
      int cx0, cx1, cy0, cy1, cz0, cz1;
      if (it == 7) {  // exactness fallback: full grid
        cx0 = cy0 = cz0 = 0;
        cx1 = cy1 = cz1 = NG - 1;
        r2 = INFINITY;
      } else {
        r2 = __fmul_rn(r, r);
        cx0 = cellof(si.x - r);
        cx1 = cellof(si.x + r);
        cy0 = cellof(si.y - r);
        cy1 = cellof(si.y + r);
        cz0 = cellof(si.z - r);
        cz1 = cellof(si.z + r);
      }
#pragma unroll
      for (int k = 0; k < K; ++k) {
        vd[k] = INFINITY;
        vi[k] = 0;
      }
      int cnt = 0;
      for (int cz = cz0; cz <= cz1; ++cz)
        for (int cy = cy0; cy <= cy1; ++cy) {
          int base = (cz << 10) | (cy << 5);
          int st = offs[base + cx0];
          int en = offs[base + cx1 + 1];
          for (int p = st + glane; p < en; p += 16) {
            float4 sj = s4s[p];
            float dot =
                fmaf(si.z, sj.z, fmaf(si.y, sj.y, __fmul_rn(si.x, sj.x)));
            float d2 = __fsub_rn(__fadd_rn(sqi, sj.w), __fmul_rn(2.0f, dot));
            if (d2 <= r2) {
              ++cnt;
              if (d2 < vd[K - 1]) {
                TOPK_INSERT(vd, vi, d2, p);
              }
            }
          }
        }
      cnt += __shfl_xor(cnt, 1);
      cnt += __shfl_xor(cnt, 2);
      cnt += __shfl_xor(cnt, 4);
      cnt += __shfl_xor(cnt, 8);
      gdone = (cnt >= K);
      if (!gdone) r = __fmul_rn(r, 1.6f);
    }
  }

  // ---- in-group extraction merge: rank e -> lane e ----
  float sel_d = INFINITY;
  int sel_i = 0;
#pragma unroll
  for (int e = 0; e < K; ++e) {
    float m = vd[0];
    int mi = vi[0];
#pragma unroll
    for (int s = 1; s < K; s <<= 1) {
      float om = __shfl_xor(m, s);
      int oi = __shfl_xor(mi, s);
      if (om < m || (om == m && oi < mi)) {
        m = om;
        mi = oi;
      }
    }
    if (glane == e) {
      sel_d = m;
      sel_i = mi;
    }
    if (vd[0] == m && vi[0] == mi) {  // winner lane pops its head
#pragma unroll
      for (int k = 0; k < K - 1; ++k) {
        vd[k] = vd[k + 1];
        vi[k] = vi[k + 1];
      }
      vd[K - 1] = INFINITY;
    }
  }

  // ---- lane-parallel aggregation over the group's 16 selected ----
  float w = expf(-10.0f * fmaxf(sel_d, 0.f));
  float4 hh = h4s[sel_i];
  float m0 = __fmul_rn(hh.x, w);
  float m1 = __fmul_rn(hh.y, w);
  float m2 = __fmul_rn(hh.z, w);
  float x0 = m0, x1 = m1, x2 = m2;
#pragma unroll
  for (int s = 1; s < K; s <<= 1) {
    m0 += __shfl_xor(m0, s);
    m1 += __shfl_xor(m1, s);
    m2 += __shfl_xor(m2, s);
    x0 = fmaxf(x0, __shfl_xor(x0, s));
    x1 = fmaxf(x1, __shfl_xor(x1, s));
    x2 = fmaxf(x2, __shfl_xor(x2, s));
  }
  if (glane == 0) {
    int oq = idxs[P];
    float* a = &aggr[(size_t)oq * 8];
    const float inv = 1.0f / 16.0f;
    a[0] = m0 * inv;
    a[1] = m1 * inv;
    a[2] = m2 * inv;
    a[3] = x0;
    a[4] = x1;
    a[5] = x2;
  }
}

// ---------------------------------------------------------------------------
// Kernel 5: latent = x@W_o1 + (aggr@W_o2 + b_o2); beta = clip(sigmoid(...)).
// Coalesced x loads + latent stores via LDS.
// ---------------------------------------------------------------------------
__global__ __launch_bounds__(64) void out_kernel(
    const float* __restrict__ x, const float* __restrict__ aggr,
    const float* __restrict__ Wo1, const float* __restrict__ Wo2,
    const float* __restrict__ bo2, const float* __restrict__ Wb,
    const float* __restrict__ bb, float* __restrict__ out) {
  __shared__ float lWo1[D * D];
  __shared__ float lWo2[6 * D];
  __shared__ float lbo2[D], lWb[D];
  __shared__ float lbb;
  __shared__ float xl[64 * D];
  __shared__ float latl[64 * D];
  for (int t = threadIdx.x; t < D * D; t += 64) lWo1[t] = Wo1[t];
  for (int t = threadIdx.x; t < 6 * D; t += 64) lWo2[t] = Wo2[t];
  if (threadIdx.x < D) {
    lbo2[threadIdx.x] = bo2[threadIdx.x];
    lWb[threadIdx.x] = Wb[threadIdx.x];
  }
  if (threadIdx.x == 0) lbb = bb[0];
  const float* xb = x + (size_t)blockIdx.x * 64 * D;
  for (int j = threadIdx.x; j < 64 * D; j += 64) xl[j] = xb[j];
  __syncthreads();

  int i = blockIdx.x * 64 + threadIdx.x;
  float ag[6];
#pragma unroll
  for (int p = 0; p < 6; ++p) ag[p] = aggr[(size_t)i * 8 + p];

  float z = 0.f;
#pragma unroll
  for (int o = 0; o < D; ++o) {
    float a = 0.f;
#pragma unroll
    for (int d = 0; d < D; ++d)
      a = fmaf(xl[threadIdx.x * D + d], lWo1[d * D + o], a);
    float b2 = 0.f;
#pragma unroll
    for (int p = 0; p < 6; ++p) b2 = fmaf(ag[p], lWo2[p * D + o], b2);
    b2 = __fadd_rn(b2, lbo2[o]);
    float lat = __fadd_rn(a, b2);
    latl[threadIdx.x * D + o] = lat;
    z = fmaf(lat, lWb[o], z);
  }
  z = __fadd_rn(z, lbb);
  float beta = 1.0f / (1.0f + expf(-z));
  out[i] = fminf(fmaxf(beta, 1e-6f), 1.0f - 1e-6f);
  __syncthreads();
  float* ob = out + N + (size_t)blockIdx.x * 64 * D;
  for (int j = threadIdx.x; j < 64 * D; j += 64) ob[j] = latl[j];
}

// ---------------------------------------------------------------------------
extern "C" void kernel_launch(void* const* d_in, const int* in_sizes, int n_in,
                              void* d_out, int out_size, void* d_ws,
                              size_t ws_size, hipStream_t stream) {
  const float* x = (const float*)d_in[0];
  const float* Ws = (const float*)d_in[1];
  const float* bs = (const float*)d_in[2];
  const float* Wh = (const float*)d_in[3];
  const float* bh = (const float*)d_in[4];
  const float* Wo1 = (const float*)d_in[5];
  const float* Wo2 = (const float*)d_in[6];
  const float* bo2 = (const float*)d_in[7];
  const float* Wb = (const float*)d_in[8];
  const float* bb = (const float*)d_in[9];
  float* out = (float*)d_out;

  // ws (floats): s4[N*4] | h4[N*4] | s4s[N*4] | h4s[N*4] | aggr[N*8] |
  // idxs[N]i | hist[32768]i | cnt2[32768]i | offs[32769]i   (~2.0 MB)
  float* ws = (float*)d_ws;
  float4* s4 = (float4*)ws;
  float4* h4 = (float4*)(ws + (size_t)N * 4);
  float4* s4s = (float4*)(ws + (size_t)N * 8);
  float4* h4s = (float4*)(ws + (size_t)N * 12);
  float* aggr = ws + (size_t)N * 16;
  int* idxs = (int*)(ws + (size_t)N * 24);
  int* hist = idxs + N;
  int* cnt2 = hist + NCELL;
  int* offs = cnt2 + NCELL;

  zero_kernel<<<NCELL / 256, 256, 0, stream>>>(hist, cnt2);
  prep_kernel<<<N / 64, 64, 0, stream>>>(x, Ws, bs, Wh, bh, s4, h4, hist);
  scan_kernel<<<1, 1024, 0, stream>>>(hist, offs);
  scatter_kernel<<<N / 64, 64, 0, stream>>>(s4, h4, offs, cnt2, s4s, h4s,
                                            idxs);
  knn_kernel<<<N / 16, 256, 0, stream>>>(s4s, h4s, idxs, offs, aggr);
  out_kernel<<<N / 64, 64, 0, stream>>>(x, aggr, Wo1, Wo2, bo2, Wb, bb, out);
}

// Round 6
// 522.167 us; speedup vs baseline: 1.7135x; 1.7135x over previous
//
#include <hip/hip_runtime.h>
#include <math.h>

#define N 16384
#define D 23
#define K 16
#define NG 32               // cells per dim
#define NCELL (NG * NG * NG)
#define GINV 4.0f           // 1/cell width (cell = 0.25)
#define GOFF 4.0f           // domain [-4,4)

__device__ __forceinline__ int cellof(float v) {
  int b = (int)((v + GOFF) * GINV);
  return b < 0 ? 0 : (b > NG - 1 ? NG - 1 : b);
}

// Sorted ascending insert of (d2, jj) into register lists vald/vali (K deep).
// Safe for any d2 (no-op when d2 >= vald[K-1]).
#define TOPK_INSERT(vald, vali, d2v, jjv)                          \
  {                                                                \
    bool ck = (d2v) < vald[K - 1];                                 \
    _Pragma("unroll") for (int k = K - 1; k >= 0; --k) {           \
      bool ckm1 = (k > 0) ? ((d2v) < vald[k - 1]) : false;         \
      float nv = ckm1 ? vald[k - 1] : (ck ? (d2v) : vald[k]);      \
      int ni = ckm1 ? vali[k - 1] : (ck ? (jjv) : vali[k]);        \
      vald[k] = nv;                                                \
      vali[k] = ni;                                                \
      ck = ckm1;                                                   \
    }                                                              \
  }

// ---------------------------------------------------------------------------
// Kernel 0: zero hist + cnt2 (32768 ints each).
// ---------------------------------------------------------------------------
__global__ __launch_bounds__(256) void zero_kernel(int* __restrict__ hist,
                                                   int* __restrict__ cnt2) {
  int i = blockIdx.x * 256 + threadIdx.x;
  hist[i] = 0;
  cnt2[i] = 0;
}

// ---------------------------------------------------------------------------
// Kernel 1: s = x@W_s + b_s, h = x@W_h + b_h; pack s4={sx,sy,sz,sq}, h4;
//           3-D cell histogram. Coalesced x via LDS staging.
// ---------------------------------------------------------------------------
__global__ __launch_bounds__(64) void prep_kernel(
    const float* __restrict__ x, const float* __restrict__ Ws,
    const float* __restrict__ bs, const float* __restrict__ Wh,
    const float* __restrict__ bh, float4* __restrict__ s4,
    float4* __restrict__ h4, int* __restrict__ hist) {
  __shared__ float lWs[D * 3], lWh[D * 3], lbs[3], lbh[3];
  __shared__ float xl[64 * D];
  for (int t = threadIdx.x; t < D * 3; t += 64) {
    lWs[t] = Ws[t];
    lWh[t] = Wh[t];
  }
  if (threadIdx.x < 3) {
    lbs[threadIdx.x] = bs[threadIdx.x];
    lbh[threadIdx.x] = bh[threadIdx.x];
  }
  const float* xb = x + (size_t)blockIdx.x * 64 * D;
  for (int j = threadIdx.x; j < 64 * D; j += 64) xl[j] = xb[j];
  __syncthreads();

  int i = blockIdx.x * 64 + threadIdx.x;
  float a0 = 0.f, a1 = 0.f, a2 = 0.f;
  float g0 = 0.f, g1 = 0.f, g2 = 0.f;
#pragma unroll
  for (int d = 0; d < D; ++d) {
    float xv = xl[threadIdx.x * D + d];
    a0 = fmaf(xv, lWs[d * 3 + 0], a0);
    a1 = fmaf(xv, lWs[d * 3 + 1], a1);
    a2 = fmaf(xv, lWs[d * 3 + 2], a2);
    g0 = fmaf(xv, lWh[d * 3 + 0], g0);
    g1 = fmaf(xv, lWh[d * 3 + 1], g1);
    g2 = fmaf(xv, lWh[d * 3 + 2], g2);
  }
  float s0 = __fadd_rn(a0, lbs[0]);
  float s1 = __fadd_rn(a1, lbs[1]);
  float s2 = __fadd_rn(a2, lbs[2]);
  float sq = fmaf(s2, s2, fmaf(s1, s1, __fmul_rn(s0, s0)));
  s4[i] = make_float4(s0, s1, s2, sq);
  h4[i] = make_float4(__fadd_rn(g0, lbh[0]), __fadd_rn(g1, lbh[1]),
                      __fadd_rn(g2, lbh[2]), 0.f);
  int cid = (cellof(s2) << 10) | (cellof(s1) << 5) | cellof(s0);
  atomicAdd(&hist[cid], 1);
}

// ---------------------------------------------------------------------------
// Kernel 2: exclusive prefix sum of hist[32768] -> offs[32769]. One block.
// ---------------------------------------------------------------------------
__global__ __launch_bounds__(1024) void scan_kernel(const int* __restrict__ hist,
                                                    int* __restrict__ offs) {
  __shared__ int wsum[16];
  int t = threadIdx.x;
  int loc[32];
  int s = 0;
#pragma unroll
  for (int j = 0; j < 32; ++j) {
    loc[j] = hist[t * 32 + j];
    s += loc[j];
  }
  int lane = t & 63, wid = t >> 6;
  int v = s;
#pragma unroll
  for (int off = 1; off < 64; off <<= 1) {
    int o = __shfl_up(v, off);
    if (lane >= off) v += o;
  }
  if (lane == 63) wsum[wid] = v;
  __syncthreads();
  if (t == 0) {
    int acc = 0;
#pragma unroll
    for (int w = 0; w < 16; ++w) {
      int tmp = wsum[w];
      wsum[w] = acc;
      acc += tmp;
    }
  }
  __syncthreads();
  int run = wsum[wid] + (v - s);  // global exclusive prefix
#pragma unroll
  for (int j = 0; j < 32; ++j) {
    offs[t * 32 + j] = run;
    run += loc[j];
  }
  if (t == 1023) offs[NCELL] = run;  // == N
}

// ---------------------------------------------------------------------------
// Kernel 3: scatter into cell-sorted layout (+ sorted h, orig index)
// ---------------------------------------------------------------------------
__global__ __launch_bounds__(64) void scatter_kernel(
    const float4* __restrict__ s4, const float4* __restrict__ h4,
    const int* __restrict__ offs, int* __restrict__ cnt2,
    float4* __restrict__ s4s, float4* __restrict__ h4s,
    int* __restrict__ idxs) {
  int i = blockIdx.x * 64 + threadIdx.x;
  float4 s = s4[i];
  int cid = (cellof(s.z) << 10) | (cellof(s.y) << 5) | cellof(s.x);
  int pos = offs[cid] + atomicAdd(&cnt2[cid], 1);
  s4s[pos] = s;
  h4s[pos] = h4[i];
  idxs[pos] = i;
}

// ---------------------------------------------------------------------------
// Kernel 4: kNN + aggregate. ONE QUERY PER WAVE (4 waves/block, no
// __syncthreads -> waves drain independently).
// Phase A: window rows' (st,en) fetched in parallel (lane r -> row r) into
//          per-wave LDS (batched by 64).
// Phase B: rows scanned with 64-lane coalesced float4 loads; cnt counts
//          d2<=r^2; per-lane top-16 with r^2-gated inserts (rare).
// Cert: cnt>=16 => exact (ball(r) subset of window); else r*=1.6 rescan;
// it==5 full-grid coalesced sweep (exact, bounded ~3us).
// Merge: 16-round 64-lane argmin extraction, rank e -> lane e; lane-parallel
// aggregation on lanes 0..15.
// ---------------------------------------------------------------------------
__global__ __launch_bounds__(256) void knn_kernel(
    const float4* __restrict__ s4s, const float4* __restrict__ h4s,
    const int* __restrict__ idxs, const int* __restrict__ offs,
    float* __restrict__ aggr) {
  __shared__ int rst[4][64], ren[4][64];
  int w = threadIdx.x >> 6;
  int lane = threadIdx.x & 63;
  int P = blockIdx.x * 4 + w;  // sorted query position
  float4 si = s4s[P];
  float sqi = si.w;
  // Gaussian 16-NN radius estimate * 1.25 safety
  float r = 0.1925f * __expf(sqi * 0.16666667f);

  float vd[K];
  int vi[K];
  bool done = false;

  for (int it = 0; it < 6 && !done; ++it) {
#pragma unroll
    for (int k = 0; k < K; ++k) {
      vd[k] = INFINITY;
      vi[k] = 0;
    }
    int cnt = 0;
    if (it < 5) {
      float r2 = __fmul_rn(r, r);
      int cx0 = cellof(si.x - r), cx1 = cellof(si.x + r);
      int cy0 = cellof(si.y - r), cy1 = cellof(si.y + r);
      int cz0 = cellof(si.z - r), cz1 = cellof(si.z + r);
      int ny = cy1 - cy0 + 1;
      int R = (cz1 - cz0 + 1) * ny;
      for (int rb = 0; rb < R; rb += 64) {
        int rid = rb + lane;
        if (rid < R) {  // parallel row fetch: kills the serial offs chain
          int cz = cz0 + rid / ny;
          int cy = cy0 + rid % ny;
          int base = (cz << 10) | (cy << 5);
          rst[w][lane] = offs[base + cx0];
          ren[w][lane] = offs[base + cx1 + 1];
        }
        int nb = (R - rb < 64) ? (R - rb) : 64;
        for (int rr = 0; rr < nb; ++rr) {
          int st = rst[w][rr], en = ren[w][rr];
          for (int p0 = st; p0 < en; p0 += 64) {
            int p = p0 + lane;
            if (p < en) {
              float4 sj = s4s[p];
              float dot =
                  fmaf(si.z, sj.z, fmaf(si.y, sj.y, __fmul_rn(si.x, sj.x)));
              float d2 =
                  __fsub_rn(__fadd_rn(sqi, sj.w), __fmul_rn(2.0f, dot));
              if (d2 <= r2) {
                ++cnt;
                if (d2 < vd[K - 1]) {
                  TOPK_INSERT(vd, vi, d2, p);
                }
              }
            }
          }
        }
      }
    } else {  // full-grid fallback: contiguous coalesced sweep, exact
      for (int p0 = 0; p0 < N; p0 += 64) {
        int p = p0 + lane;
        float4 sj = s4s[p];
        float dot = fmaf(si.z, sj.z, fmaf(si.y, sj.y, __fmul_rn(si.x, sj.x)));
        float d2 = __fsub_rn(__fadd_rn(sqi, sj.w), __fmul_rn(2.0f, dot));
        ++cnt;
        if (d2 < vd[K - 1]) {
          TOPK_INSERT(vd, vi, d2, p);
        }
      }
    }
    cnt += __shfl_xor(cnt, 1);
    cnt += __shfl_xor(cnt, 2);
    cnt += __shfl_xor(cnt, 4);
    cnt += __shfl_xor(cnt, 8);
    cnt += __shfl_xor(cnt, 16);
    cnt += __shfl_xor(cnt, 32);
    done = (cnt >= K);
    if (!done) r = __fmul_rn(r, 1.6f);
  }

  // ---- exact merge: 16-round 64-lane argmin extraction ----
  float sel_d = INFINITY;
  int sel_i = 0;
#pragma unroll
  for (int e = 0; e < K; ++e) {
    float m = vd[0];
    int mi = vi[0];
#pragma unroll
    for (int s = 1; s < 64; s <<= 1) {
      float om = __shfl_xor(m, s);
      int oi = __shfl_xor(mi, s);
      if (om < m || (om == m && oi < mi)) {
        m = om;
        mi = oi;
      }
    }
    if (lane == e) {
      sel_d = m;
      sel_i = mi;
    }
    if (vd[0] == m && vi[0] == mi) {  // winner lane pops its head
#pragma unroll
      for (int k = 0; k < K - 1; ++k) {
        vd[k] = vd[k + 1];
        vi[k] = vi[k + 1];
      }
      vd[K - 1] = INFINITY;
    }
  }

  // ---- lane-parallel aggregation on lanes 0..15 ----
  float ww = expf(-10.0f * fmaxf(sel_d, 0.f));
  float4 hh = h4s[sel_i];
  float m0 = __fmul_rn(hh.x, ww);
  float m1 = __fmul_rn(hh.y, ww);
  float m2 = __fmul_rn(hh.z, ww);
  float x0 = m0, x1 = m1, x2 = m2;
#pragma unroll
  for (int s = 1; s < K; s <<= 1) {
    m0 += __shfl_xor(m0, s);
    m1 += __shfl_xor(m1, s);
    m2 += __shfl_xor(m2, s);
    x0 = fmaxf(x0, __shfl_xor(x0, s));
    x1 = fmaxf(x1, __shfl_xor(x1, s));
    x2 = fmaxf(x2, __shfl_xor(x2, s));
  }
  if (lane == 0) {
    int oq = idxs[P];
    float* a = &aggr[(size_t)oq * 8];
    const float inv = 1.0f / 16.0f;
    a[0] = m0 * inv;
    a[1] = m1 * inv;
    a[2] = m2 * inv;
    a[3] = x0;
    a[4] = x1;
    a[5] = x2;
  }
}

// ---------------------------------------------------------------------------
// Kernel 5: latent = x@W_o1 + (aggr@W_o2 + b_o2); beta = clip(sigmoid(...)).
// ---------------------------------------------------------------------------
__global__ __launch_bounds__(64) void out_kernel(
    const float* __restrict__ x, const float* __restrict__ aggr,
    const float* __restrict__ Wo1, const float* __restrict__ Wo2,
    const float* __restrict__ bo2, const float* __restrict__ Wb,
    const float* __restrict__ bb, float* __restrict__ out) {
  __shared__ float lWo1[D * D];
  __shared__ float lWo2[6 * D];
  __shared__ float lbo2[D], lWb[D];
  __shared__ float lbb;
  __shared__ float xl[64 * D];
  __shared__ float latl[64 * D];
  for (int t = threadIdx.x; t < D * D; t += 64) lWo1[t] = Wo1[t];
  for (int t = threadIdx.x; t < 6 * D; t += 64) lWo2[t] = Wo2[t];
  if (threadIdx.x < D) {
    lbo2[threadIdx.x] = bo2[threadIdx.x];
    lWb[threadIdx.x] = Wb[threadIdx.x];
  }
  if (threadIdx.x == 0) lbb = bb[0];
  const float* xb = x + (size_t)blockIdx.x * 64 * D;
  for (int j = threadIdx.x; j < 64 * D; j += 64) xl[j] = xb[j];
  __syncthreads();

  int i = blockIdx.x * 64 + threadIdx.x;
  float ag[6];
#pragma unroll
  for (int p = 0; p < 6; ++p) ag[p] = aggr[(size_t)i * 8 + p];

  float z = 0.f;
#pragma unroll
  for (int o = 0; o < D; ++o) {
    float a = 0.f;
#pragma unroll
    for (int d = 0; d < D; ++d)
      a = fmaf(xl[threadIdx.x * D + d], lWo1[d * D + o], a);
    float b2 = 0.f;
#pragma unroll
    for (int p = 0; p < 6; ++p) b2 = fmaf(ag[p], lWo2[p * D + o], b2);
    b2 = __fadd_rn(b2, lbo2[o]);
    float lat = __fadd_rn(a, b2);
    latl[threadIdx.x * D + o] = lat;
    z = fmaf(lat, lWb[o], z);
  }
  z = __fadd_rn(z, lbb);
  float beta = 1.0f / (1.0f + expf(-z));
  out[i] = fminf(fmaxf(beta, 1e-6f), 1.0f - 1e-6f);
  __syncthreads();
  float* ob = out + N + (size_t)blockIdx.x * 64 * D;
  for (int j = threadIdx.x; j < 64 * D; j += 64) ob[j] = latl[j];
}

// ---------------------------------------------------------------------------
extern "C" void kernel_launch(void* const* d_in, const int* in_sizes, int n_in,
                              void* d_out, int out_size, void* d_ws,
                              size_t ws_size, hipStream_t stream) {
  const float* x = (const float*)d_in[0];
  const float* Ws = (const float*)d_in[1];
  const float* bs = (const float*)d_in[2];
  const float* Wh = (const float*)d_in[3];
  const float* bh = (const float*)d_in[4];
  const float* Wo1 = (const float*)d_in[5];
  const float* Wo2 = (const float*)d_in[6];
  const float* bo2 = (const float*)d_in[7];
  const float* Wb = (const float*)d_in[8];
  const float* bb = (const float*)d_in[9];
  float* out = (float*)d_out;

  // ws (floats): s4[N*4] | h4[N*4] | s4s[N*4] | h4s[N*4] | aggr[N*8] |
  // idxs[N]i | hist[32768]i | cnt2[32768]i | offs[32769]i   (~2.0 MB)
  float* ws = (float*)d_ws;
  float4* s4 = (float4*)ws;
  float4* h4 = (float4*)(ws + (size_t)N * 4);
  float4* s4s = (float4*)(ws + (size_t)N * 8);
  float4* h4s = (float4*)(ws + (size_t)N * 12);
  float* aggr = ws + (size_t)N * 16;
  int* idxs = (int*)(ws + (size_t)N * 24);
  int* hist = idxs + N;
  int* cnt2 = hist + NCELL;
  int* offs = cnt2 + NCELL;

  zero_kernel<<<NCELL / 256, 256, 0, stream>>>(hist, cnt2);
  prep_kernel<<<N / 64, 64, 0, stream>>>(x, Ws, bs, Wh, bh, s4, h4, hist);
  scan_kernel<<<1, 1024, 0, stream>>>(hist, offs);
  scatter_kernel<<<N / 64, 64, 0, stream>>>(s4, h4, offs, cnt2, s4s, h4s,
                                            idxs);
  knn_kernel<<<N / 4, 256, 0, stream>>>(s4s, h4s, idxs, offs, aggr);
  out_kernel<<<N / 64, 64, 0, stream>>>(x, aggr, Wo1, Wo2, bo2, Wb, bb, out);
}

// Round 7
// 214.540 us; speedup vs baseline: 4.1704x; 2.4339x over previous
//
#include <hip/hip_runtime.h>
#include <math.h>

#define N 16384
#define D 23
#define K 16
#define NG 32               // cells per dim
#define NCELL (NG * NG * NG)
#define GINV 4.0f           // 1/cell width (cell = 0.25)
#define GOFF 4.0f           // domain [-4,4)
#define CAP 192             // per-wave candidate buffer

__device__ __forceinline__ int cellof(float v) {
  int b = (int)((v + GOFF) * GINV);
  return b < 0 ? 0 : (b > NG - 1 ? NG - 1 : b);
}

// ---------------------------------------------------------------------------
// Kernel 0: zero hist + cnt2 (32768 ints each).
// ---------------------------------------------------------------------------
__global__ __launch_bounds__(256) void zero_kernel(int* __restrict__ hist,
                                                   int* __restrict__ cnt2) {
  int i = blockIdx.x * 256 + threadIdx.x;
  hist[i] = 0;
  cnt2[i] = 0;
}

// ---------------------------------------------------------------------------
// Kernel 1: s = x@W_s + b_s, h = x@W_h + b_h; pack s4={sx,sy,sz,sq}, h4;
//           3-D cell histogram. Coalesced x via LDS staging.
// ---------------------------------------------------------------------------
__global__ __launch_bounds__(64) void prep_kernel(
    const float* __restrict__ x, const float* __restrict__ Ws,
    const float* __restrict__ bs, const float* __restrict__ Wh,
    const float* __restrict__ bh, float4* __restrict__ s4,
    float4* __restrict__ h4, int* __restrict__ hist) {
  __shared__ float lWs[D * 3], lWh[D * 3], lbs[3], lbh[3];
  __shared__ float xl[64 * D];
  for (int t = threadIdx.x; t < D * 3; t += 64) {
    lWs[t] = Ws[t];
    lWh[t] = Wh[t];
  }
  if (threadIdx.x < 3) {
    lbs[threadIdx.x] = bs[threadIdx.x];
    lbh[threadIdx.x] = bh[threadIdx.x];
  }
  const float* xb = x + (size_t)blockIdx.x * 64 * D;
  for (int j = threadIdx.x; j < 64 * D; j += 64) xl[j] = xb[j];
  __syncthreads();

  int i = blockIdx.x * 64 + threadIdx.x;
  float a0 = 0.f, a1 = 0.f, a2 = 0.f;
  float g0 = 0.f, g1 = 0.f, g2 = 0.f;
#pragma unroll
  for (int d = 0; d < D; ++d) {
    float xv = xl[threadIdx.x * D + d];
    a0 = fmaf(xv, lWs[d * 3 + 0], a0);
    a1 = fmaf(xv, lWs[d * 3 + 1], a1);
    a2 = fmaf(xv, lWs[d * 3 + 2], a2);
    g0 = fmaf(xv, lWh[d * 3 + 0], g0);
    g1 = fmaf(xv, lWh[d * 3 + 1], g1);
    g2 = fmaf(xv, lWh[d * 3 + 2], g2);
  }
  float s0 = __fadd_rn(a0, lbs[0]);
  float s1 = __fadd_rn(a1, lbs[1]);
  float s2 = __fadd_rn(a2, lbs[2]);
  float sq = fmaf(s2, s2, fmaf(s1, s1, __fmul_rn(s0, s0)));
  s4[i] = make_float4(s0, s1, s2, sq);
  h4[i] = make_float4(__fadd_rn(g0, lbh[0]), __fadd_rn(g1, lbh[1]),
                      __fadd_rn(g2, lbh[2]), 0.f);
  int cid = (cellof(s2) << 10) | (cellof(s1) << 5) | cellof(s0);
  atomicAdd(&hist[cid], 1);
}

// ---------------------------------------------------------------------------
// Kernel 2: exclusive prefix sum of hist[32768] -> offs[32769]. One block.
// ---------------------------------------------------------------------------
__global__ __launch_bounds__(1024) void scan_kernel(const int* __restrict__ hist,
                                                    int* __restrict__ offs) {
  __shared__ int wsum[16];
  int t = threadIdx.x;
  int loc[32];
  int s = 0;
#pragma unroll
  for (int j = 0; j < 32; ++j) {
    loc[j] = hist[t * 32 + j];
    s += loc[j];
  }
  int lane = t & 63, wid = t >> 6;
  int v = s;
#pragma unroll
  for (int off = 1; off < 64; off <<= 1) {
    int o = __shfl_up(v, off);
    if (lane >= off) v += o;
  }
  if (lane == 63) wsum[wid] = v;
  __syncthreads();
  if (t == 0) {
    int acc = 0;
#pragma unroll
    for (int w = 0; w < 16; ++w) {
      int tmp = wsum[w];
      wsum[w] = acc;
      acc += tmp;
    }
  }
  __syncthreads();
  int run = wsum[wid] + (v - s);  // global exclusive prefix
#pragma unroll
  for (int j = 0; j < 32; ++j) {
    offs[t * 32 + j] = run;
    run += loc[j];
  }
  if (t == 1023) offs[NCELL] = run;  // == N
}

// ---------------------------------------------------------------------------
// Kernel 3: scatter into cell-sorted layout (+ sorted h, orig index)
// ---------------------------------------------------------------------------
__global__ __launch_bounds__(64) void scatter_kernel(
    const float4* __restrict__ s4, const float4* __restrict__ h4,
    const int* __restrict__ offs, int* __restrict__ cnt2,
    float4* __restrict__ s4s, float4* __restrict__ h4s,
    int* __restrict__ idxs) {
  int i = blockIdx.x * 64 + threadIdx.x;
  float4 s = s4[i];
  int cid = (cellof(s.z) << 10) | (cellof(s.y) << 5) | cellof(s.x);
  int pos = offs[cid] + atomicAdd(&cnt2[cid], 1);
  s4s[pos] = s;
  h4s[pos] = h4[i];
  idxs[pos] = i;
}

// ---------------------------------------------------------------------------
// Kernel 4: kNN + aggregate. ONE QUERY PER WAVE, count+append streaming.
// Per retry: window cells from radius r; per cz-layer ONE contiguous span
// [offs(cz,cy0,cx0), offs(cz,cy1,cx1+1)) (superset of window; ball(r) subset
// of spans). Scan = coalesced 64-lane float4 rounds; candidates with d2<=r^2
// ballot-compacted into per-wave LDS buffer (cap 192) + exact wave count.
// Accept when 16<=cnt<=192 (exact certificate); cnt<16 grow, cnt>192 bisect.
// Then 16-round wave-argmin selection over <=3 buffered entries/lane, and
// lane-parallel aggregation on lanes 0..15. No __syncthreads anywhere.
// ---------------------------------------------------------------------------
__global__ __launch_bounds__(256) void knn_kernel(
    const float4* __restrict__ s4s, const float4* __restrict__ h4s,
    const int* __restrict__ idxs, const int* __restrict__ offs,
    float* __restrict__ aggr) {
  __shared__ float bufd[4][CAP];
  __shared__ int bufi[4][CAP];
  int w = threadIdx.x >> 6;
  int lane = threadIdx.x & 63;
  int P = blockIdx.x * 4 + w;  // sorted query position
  float4 si = s4s[P];
  float sqi = si.w;
  // Gaussian 16-NN radius estimate * 1.25 safety, capped (tail queries
  // over-estimate massively; growth loop recovers cheaply)
  float r = fminf(0.1925f * __expf(sqi * 0.16666667f), 0.8f);
  float rlo = 0.f, rhi = 0.f;  // bisection state (rhi==0 -> unset)

  int cnt = 0;
  for (int it = 0; it < 16; ++it) {
    float r2 = __fmul_rn(r, r);
    int cx0 = cellof(si.x - r), cx1 = cellof(si.x + r);
    int cy0 = cellof(si.y - r), cy1 = cellof(si.y + r);
    int cz0 = cellof(si.z - r), cz1 = cellof(si.z + r);
    int nz = cz1 - cz0 + 1;
    // lane-parallel span-bound fetch (lane l <-> layer cz0+l)
    int sp_st = 0, sp_en = 0;
    if (lane < nz) {
      int cz = cz0 + lane;
      sp_st = offs[(cz << 10) | (cy0 << 5) | cx0];
      sp_en = offs[((cz << 10) | (cy1 << 5)) + cx1 + 1];
    }
    cnt = 0;
    for (int l = 0; l < nz; ++l) {
      int st = __shfl(sp_st, l);
      int en = __shfl(sp_en, l);
      for (int p0 = st; p0 < en; p0 += 64) {
        int p = p0 + lane;
        bool pv = (p < en);
        int pc = pv ? p : (en - 1);
        float4 sj = s4s[pc];
        float dot = fmaf(si.z, sj.z, fmaf(si.y, sj.y, __fmul_rn(si.x, sj.x)));
        float d2 = __fsub_rn(__fadd_rn(sqi, sj.w), __fmul_rn(2.0f, dot));
        bool pred = pv && (d2 <= r2);
        unsigned long long mk = __ballot(pred);
        int below = __builtin_amdgcn_mbcnt_hi(
            (unsigned int)(mk >> 32),
            __builtin_amdgcn_mbcnt_lo((unsigned int)mk, 0));
        int slot = cnt + below;
        if (pred && slot < CAP) {
          bufd[w][slot] = d2;
          bufi[w][slot] = pc;
        }
        cnt += (int)__popcll(mk);
      }
    }
    if (cnt >= K && cnt <= CAP) break;      // exact certificate
    if (it >= 12 && cnt >= K) break;        // force-accept (P~0 path)
    if (cnt < K) {
      rlo = r;
      r = (rhi > 0.f) ? 0.5f * (rlo + rhi) : __fmul_rn(r, 1.7f);
    } else {
      rhi = r;
      r = 0.5f * (rlo + r);
    }
  }

  // ---- selection: 16-round wave-argmin over <=3 entries/lane ----
  int M = cnt < CAP ? cnt : CAP;
  float e0 = INFINITY, e1 = INFINITY, e2 = INFINITY;
  int j0 = 0x7fffffff, j1 = 0x7fffffff, j2 = 0x7fffffff;
  if (lane < M) {
    e0 = bufd[w][lane];
    j0 = bufi[w][lane];
  }
  if (lane + 64 < M) {
    e1 = bufd[w][lane + 64];
    j1 = bufi[w][lane + 64];
  }
  if (lane + 128 < M) {
    e2 = bufd[w][lane + 128];
    j2 = bufi[w][lane + 128];
  }

  float sel_d = INFINITY;
  int sel_i = 0;
#pragma unroll
  for (int e = 0; e < K; ++e) {
    // lane-local min of 3 (tie-break smaller idx)
    float lm = e0;
    int li = j0, ls = 0;
    if (e1 < lm || (e1 == lm && j1 < li)) {
      lm = e1;
      li = j1;
      ls = 1;
    }
    if (e2 < lm || (e2 == lm && j2 < li)) {
      lm = e2;
      li = j2;
      ls = 2;
    }
    // wave argmin (value, then idx)
    float m = lm;
    int mi = li;
#pragma unroll
    for (int s = 1; s < 64; s <<= 1) {
      float om = __shfl_xor(m, s);
      int oi = __shfl_xor(mi, s);
      if (om < m || (om == m && oi < mi)) {
        m = om;
        mi = oi;
      }
    }
    if (lane == e) {
      sel_d = m;
      sel_i = mi;
    }
    if (lm == m && li == mi) {  // unique winner consumes its slot
      if (ls == 0)
        e0 = INFINITY;
      else if (ls == 1)
        e1 = INFINITY;
      else
        e2 = INFINITY;
    }
  }

  // ---- lane-parallel aggregation on lanes 0..15 ----
  float ww = expf(-10.0f * fmaxf(sel_d, 0.f));
  float4 hh = h4s[sel_i];
  float m0 = __fmul_rn(hh.x, ww);
  float m1 = __fmul_rn(hh.y, ww);
  float m2 = __fmul_rn(hh.z, ww);
  float x0 = m0, x1 = m1, x2 = m2;
#pragma unroll
  for (int s = 1; s < K; s <<= 1) {
    m0 += __shfl_xor(m0, s);
    m1 += __shfl_xor(m1, s);
    m2 += __shfl_xor(m2, s);
    x0 = fmaxf(x0, __shfl_xor(x0, s));
    x1 = fmaxf(x1, __shfl_xor(x1, s));
    x2 = fmaxf(x2, __shfl_xor(x2, s));
  }
  if (lane == 0) {
    int oq = idxs[P];
    float* a = &aggr[(size_t)oq * 8];
    const float inv = 1.0f / 16.0f;
    a[0] = m0 * inv;
    a[1] = m1 * inv;
    a[2] = m2 * inv;
    a[3] = x0;
    a[4] = x1;
    a[5] = x2;
  }
}

// ---------------------------------------------------------------------------
// Kernel 5: latent = x@W_o1 + (aggr@W_o2 + b_o2); beta = clip(sigmoid(...)).
// ---------------------------------------------------------------------------
__global__ __launch_bounds__(64) void out_kernel(
    const float* __restrict__ x, const float* __restrict__ aggr,
    const float* __restrict__ Wo1, const float* __restrict__ Wo2,
    const float* __restrict__ bo2, const float* __restrict__ Wb,
    const float* __restrict__ bb, float* __restrict__ out) {
  __shared__ float lWo1[D * D];
  __shared__ float lWo2[6 * D];
  __shared__ float lbo2[D], lWb[D];
  __shared__ float lbb;
  __shared__ float xl[64 * D];
  __shared__ float latl[64 * D];
  for (int t = threadIdx.x; t < D * D; t += 64) lWo1[t] = Wo1[t];
  for (int t = threadIdx.x; t < 6 * D; t += 64) lWo2[t] = Wo2[t];
  if (threadIdx.x < D) {
    lbo2[threadIdx.x] = bo2[threadIdx.x];
    lWb[threadIdx.x] = Wb[threadIdx.x];
  }
  if (threadIdx.x == 0) lbb = bb[0];
  const float* xb = x + (size_t)blockIdx.x * 64 * D;
  for (int j = threadIdx.x; j < 64 * D; j += 64) xl[j] = xb[j];
  __syncthreads();

  int i = blockIdx.x * 64 + threadIdx.x;
  float ag[6];
#pragma unroll
  for (int p = 0; p < 6; ++p) ag[p] = aggr[(size_t)i * 8 + p];

  float z = 0.f;
#pragma unroll
  for (int o = 0; o < D; ++o) {
    float a = 0.f;
#pragma unroll
    for (int d = 0; d < D; ++d)
      a = fmaf(xl[threadIdx.x * D + d], lWo1[d * D + o], a);
    float b2 = 0.f;
#pragma unroll
    for (int p = 0; p < 6; ++p) b2 = fmaf(ag[p], lWo2[p * D + o], b2);
    b2 = __fadd_rn(b2, lbo2[o]);
    float lat = __fadd_rn(a, b2);
    latl[threadIdx.x * D + o] = lat;
    z = fmaf(lat, lWb[o], z);
  }
  z = __fadd_rn(z, lbb);
  float beta = 1.0f / (1.0f + expf(-z));
  out[i] = fminf(fmaxf(beta, 1e-6f), 1.0f - 1e-6f);
  __syncthreads();
  float* ob = out + N + (size_t)blockIdx.x * 64 * D;
  for (int j = threadIdx.x; j < 64 * D; j += 64) ob[j] = latl[j];
}

// ---------------------------------------------------------------------------
extern "C" void kernel_launch(void* const* d_in, const int* in_sizes, int n_in,
                              void* d_out, int out_size, void* d_ws,
                              size_t ws_size, hipStream_t stream) {
  const float* x = (const float*)d_in[0];
  const float* Ws = (const float*)d_in[1];
  const float* bs = (const float*)d_in[2];
  const float* Wh = (const float*)d_in[3];
  const float* bh = (const float*)d_in[4];
  const float* Wo1 = (const float*)d_in[5];
  const float* Wo2 = (const float*)d_in[6];
  const float* bo2 = (const float*)d_in[7];
  const float* Wb = (const float*)d_in[8];
  const float* bb = (const float*)d_in[9];
  float* out = (float*)d_out;

  // ws (floats): s4[N*4] | h4[N*4] | s4s[N*4] | h4s[N*4] | aggr[N*8] |
  // idxs[N]i | hist[32768]i | cnt2[32768]i | offs[32769]i   (~2.0 MB)
  float* ws = (float*)d_ws;
  float4* s4 = (float4*)ws;
  float4* h4 = (float4*)(ws + (size_t)N * 4);
  float4* s4s = (float4*)(ws + (size_t)N * 8);
  float4* h4s = (float4*)(ws + (size_t)N * 12);
  float* aggr = ws + (size_t)N * 16;
  int* idxs = (int*)(ws + (size_t)N * 24);
  int* hist = idxs + N;
  int* cnt2 = hist + NCELL;
  int* offs = cnt2 + NCELL;

  zero_kernel<<<NCELL / 256, 256, 0, stream>>>(hist, cnt2);
  prep_kernel<<<N / 64, 64, 0, stream>>>(x, Ws, bs, Wh, bh, s4, h4, hist);
  scan_kernel<<<1, 1024, 0, stream>>>(hist, offs);
  scatter_kernel<<<N / 64, 64, 0, stream>>>(s4, h4, offs, cnt2, s4s, h4s,
                                            idxs);
  knn_kernel<<<N / 4, 256, 0, stream>>>(s4s, h4s, idxs, offs, aggr);
  out_kernel<<<N / 64, 64, 0, stream>>>(x, aggr, Wo1, Wo2, bo2, Wb, bb, out);
}

// Round 9
// 193.031 us; speedup vs baseline: 4.6350x; 1.1114x over previous
//
#include <hip/hip_runtime.h>
#include <math.h>

#define N 16384
#define D 23
#define K 16
#define NG 32               // cells per dim
#define NCELL (NG * NG * NG)
#define GINV 4.0f           // 1/cell width (cell = 0.25)
#define GOFF 4.0f           // domain [-4,4)
#define CAP 64              // per-wave candidate buffer (one key per lane)

__device__ __forceinline__ int cellof(float v) {
  int b = (int)((v + GOFF) * GINV);
  return b < 0 ? 0 : (b > NG - 1 ? NG - 1 : b);
}
// order-preserving float->u32 (monotone, invertible)
__device__ __forceinline__ unsigned enc32(float f) {
  unsigned u = __float_as_uint(f);
  return (u & 0x80000000u) ? ~u : (u | 0x80000000u);
}
__device__ __forceinline__ float dec32(unsigned u) {
  return __uint_as_float((u & 0x80000000u) ? (u & 0x7fffffffu) : ~u);
}

// ---------------------------------------------------------------------------
// Kernel 0: zero hist + cnt2 (32768 ints each).
// ---------------------------------------------------------------------------
__global__ __launch_bounds__(256) void zero_kernel(int* __restrict__ hist,
                                                   int* __restrict__ cnt2) {
  int i = blockIdx.x * 256 + threadIdx.x;
  hist[i] = 0;
  cnt2[i] = 0;
}

// ---------------------------------------------------------------------------
// Kernel 1: s = x@W_s + b_s, h = x@W_h + b_h; pack s4={sx,sy,sz,sq}, h4;
//           3-D cell histogram. Coalesced x via LDS staging.
// ---------------------------------------------------------------------------
__global__ __launch_bounds__(64) void prep_kernel(
    const float* __restrict__ x, const float* __restrict__ Ws,
    const float* __restrict__ bs, const float* __restrict__ Wh,
    const float* __restrict__ bh, float4* __restrict__ s4,
    float4* __restrict__ h4, int* __restrict__ hist) {
  __shared__ float lWs[D * 3], lWh[D * 3], lbs[3], lbh[3];
  __shared__ float xl[64 * D];
  for (int t = threadIdx.x; t < D * 3; t += 64) {
    lWs[t] = Ws[t];
    lWh[t] = Wh[t];
  }
  if (threadIdx.x < 3) {
    lbs[threadIdx.x] = bs[threadIdx.x];
    lbh[threadIdx.x] = bh[threadIdx.x];
  }
  const float* xb = x + (size_t)blockIdx.x * 64 * D;
  for (int j = threadIdx.x; j < 64 * D; j += 64) xl[j] = xb[j];
  __syncthreads();

  int i = blockIdx.x * 64 + threadIdx.x;
  float a0 = 0.f, a1 = 0.f, a2 = 0.f;
  float g0 = 0.f, g1 = 0.f, g2 = 0.f;
#pragma unroll
  for (int d = 0; d < D; ++d) {
    float xv = xl[threadIdx.x * D + d];
    a0 = fmaf(xv, lWs[d * 3 + 0], a0);
    a1 = fmaf(xv, lWs[d * 3 + 1], a1);
    a2 = fmaf(xv, lWs[d * 3 + 2], a2);
    g0 = fmaf(xv, lWh[d * 3 + 0], g0);
    g1 = fmaf(xv, lWh[d * 3 + 1], g1);
    g2 = fmaf(xv, lWh[d * 3 + 2], g2);
  }
  float s0 = __fadd_rn(a0, lbs[0]);
  float s1 = __fadd_rn(a1, lbs[1]);
  float s2 = __fadd_rn(a2, lbs[2]);
  float sq = fmaf(s2, s2, fmaf(s1, s1, __fmul_rn(s0, s0)));
  s4[i] = make_float4(s0, s1, s2, sq);
  h4[i] = make_float4(__fadd_rn(g0, lbh[0]), __fadd_rn(g1, lbh[1]),
                      __fadd_rn(g2, lbh[2]), 0.f);
  int cid = (cellof(s2) << 10) | (cellof(s1) << 5) | cellof(s0);
  atomicAdd(&hist[cid], 1);
}

// ---------------------------------------------------------------------------
// Kernel 2: exclusive prefix sum of hist[32768] -> offs[32769]. One block.
// ---------------------------------------------------------------------------
__global__ __launch_bounds__(1024) void scan_kernel(const int* __restrict__ hist,
                                                    int* __restrict__ offs) {
  __shared__ int wsum[16];
  int t = threadIdx.x;
  int loc[32];
  int s = 0;
#pragma unroll
  for (int j = 0; j < 32; ++j) {
    loc[j] = hist[t * 32 + j];
    s += loc[j];
  }
  int lane = t & 63, wid = t >> 6;
  int v = s;
#pragma unroll
  for (int off = 1; off < 64; off <<= 1) {
    int o = __shfl_up(v, off);
    if (lane >= off) v += o;
  }
  if (lane == 63) wsum[wid] = v;
  __syncthreads();
  if (t == 0) {
    int acc = 0;
#pragma unroll
    for (int w = 0; w < 16; ++w) {
      int tmp = wsum[w];
      wsum[w] = acc;
      acc += tmp;
    }
  }
  __syncthreads();
  int run = wsum[wid] + (v - s);  // global exclusive prefix
#pragma unroll
  for (int j = 0; j < 32; ++j) {
    offs[t * 32 + j] = run;
    run += loc[j];
  }
  if (t == 1023) offs[NCELL] = run;  // == N
}

// ---------------------------------------------------------------------------
// Kernel 3: scatter into cell-sorted layout (+ sorted h, orig index)
// ---------------------------------------------------------------------------
__global__ __launch_bounds__(64) void scatter_kernel(
    const float4* __restrict__ s4, const float4* __restrict__ h4,
    const int* __restrict__ offs, int* __restrict__ cnt2,
    float4* __restrict__ s4s, float4* __restrict__ h4s,
    int* __restrict__ idxs) {
  int i = blockIdx.x * 64 + threadIdx.x;
  float4 s = s4[i];
  int cid = (cellof(s.z) << 10) | (cellof(s.y) << 5) | cellof(s.x);
  int pos = offs[cid] + atomicAdd(&cnt2[cid], 1);
  s4s[pos] = s;
  h4s[pos] = h4[i];
  idxs[pos] = i;
}

// ---------------------------------------------------------------------------
// Kernel 4: kNN + aggregate + FUSED output GEMM/beta. ONE QUERY PER WAVE.
// Scan (identical to round 7): per retry, per cz-layer one contiguous span;
// coalesced 64-lane loads; d2<=r^2 candidates ballot-compacted into per-wave
// LDS buffer (cap 64) + exact count. Accept 16<=cnt<=64 (exact certificate;
// ball(r) subset of spans); cnt<16 grow r, cnt>64 bisect down.
// Selection: u64-key (enc32(d2)|pos) bitonic sort across 64 lanes -> ranks
// 0..15 on lanes 0..15 (same (d2,idx) order as extraction merge).
// Epilogue: aggregation butterfly; broadcast group-0 aggregates; lanes 0..22
// compute latent row with reference-exact fma ordering; serial-shfl z chain
// -> beta. out_kernel eliminated.
// ---------------------------------------------------------------------------
__global__ __launch_bounds__(256) void knn_kernel(
    const float4* __restrict__ s4s, const float4* __restrict__ h4s,
    const int* __restrict__ idxs, const int* __restrict__ offs,
    const float* __restrict__ x, const float* __restrict__ Wo1,
    const float* __restrict__ Wo2, const float* __restrict__ bo2,
    const float* __restrict__ Wb, const float* __restrict__ bb,
    float* __restrict__ out) {
  __shared__ float bufd[4][CAP];
  __shared__ int bufi[4][CAP];
  __shared__ float lWo1[D * D], lWo2[6 * D], lbo2[D], lWb[D], lbb[1];
  {
    int t = threadIdx.x;
    for (int j = t; j < D * D; j += 256) lWo1[j] = Wo1[j];
    for (int j = t; j < 6 * D; j += 256) lWo2[j] = Wo2[j];
    if (t < D) {
      lbo2[t] = bo2[t];
      lWb[t] = Wb[t];
    }
    if (t == 0) lbb[0] = bb[0];
  }
  __syncthreads();

  int w = threadIdx.x >> 6;
  int lane = threadIdx.x & 63;
  int P = blockIdx.x * 4 + w;  // sorted query position
  float4 si = s4s[P];
  float sqi = si.w;
  float r = fminf(0.1925f * __expf(sqi * 0.16666667f), 0.8f);
  float rlo = 0.f, rhi = 0.f;

  int cnt = 0;
  for (int it = 0; it < 16; ++it) {
    float r2 = __fmul_rn(r, r);
    int cx0 = cellof(si.x - r), cx1 = cellof(si.x + r);
    int cy0 = cellof(si.y - r), cy1 = cellof(si.y + r);
    int cz0 = cellof(si.z - r), cz1 = cellof(si.z + r);
    int nz = cz1 - cz0 + 1;
    int sp_st = 0, sp_en = 0;
    if (lane < nz) {
      int cz = cz0 + lane;
      sp_st = offs[(cz << 10) | (cy0 << 5) | cx0];
      sp_en = offs[((cz << 10) | (cy1 << 5)) + cx1 + 1];
    }
    cnt = 0;
    for (int l = 0; l < nz; ++l) {
      int st = __shfl(sp_st, l);
      int en = __shfl(sp_en, l);
      for (int p0 = st; p0 < en; p0 += 64) {
        int p = p0 + lane;
        bool pv = (p < en);
        int pc = pv ? p : (en - 1);
        float4 sj = s4s[pc];
        float dot = fmaf(si.z, sj.z, fmaf(si.y, sj.y, __fmul_rn(si.x, sj.x)));
        float d2 = __fsub_rn(__fadd_rn(sqi, sj.w), __fmul_rn(2.0f, dot));
        bool pred = pv && (d2 <= r2);
        unsigned long long mk = __ballot(pred);
        int below = __builtin_amdgcn_mbcnt_hi(
            (unsigned)(mk >> 32), __builtin_amdgcn_mbcnt_lo((unsigned)mk, 0));
        int slot = cnt + below;
        if (pred && slot < CAP) {
          bufd[w][slot] = d2;
          bufi[w][slot] = pc;
        }
        cnt += (int)__popcll(mk);
      }
    }
    if (cnt >= K && cnt <= CAP) break;  // exact certificate
    if (it >= 12 && cnt >= K) break;    // force-accept (P~0 path)
    if (cnt < K) {
      rlo = r;
      r = (rhi > 0.f) ? 0.5f * (rlo + rhi) : __fmul_rn(r, 1.7f);
    } else {
      rhi = r;
      r = 0.5f * (rlo + r);
    }
  }

  // ---- selection: u64-key bitonic sort of 64; ranks 0..15 -> lanes 0..15 ----
  int M = cnt < CAP ? cnt : CAP;
  unsigned long long key = ~0ull;
  if (lane < M)
    key = ((unsigned long long)enc32(bufd[w][lane]) << 32) |
          (unsigned)bufi[w][lane];
#pragma unroll
  for (int kk = 2; kk <= 64; kk <<= 1) {
#pragma unroll
    for (int j = kk >> 1; j > 0; j >>= 1) {
      unsigned long long other = __shfl_xor(key, j);
      bool keepMin = ((lane & j) == 0) == ((lane & kk) == 0);
      unsigned long long mn = key < other ? key : other;
      unsigned long long mx = key < other ? other : key;
      key = keepMin ? mn : mx;
    }
  }
  float sel_d = dec32((unsigned)(key >> 32));
  int sel_i = ((int)(unsigned)(key & 0xffffffffu)) & (N - 1);

  // ---- aggregation butterfly within 16-lane groups ----
  float wwt = expf(-10.0f * fmaxf(sel_d, 0.f));
  float4 hh = h4s[sel_i];
  float m0 = __fmul_rn(hh.x, wwt);
  float m1 = __fmul_rn(hh.y, wwt);
  float m2 = __fmul_rn(hh.z, wwt);
  float x0 = m0, x1 = m1, x2 = m2;
#pragma unroll
  for (int s = 1; s < K; s <<= 1) {
    m0 += __shfl_xor(m0, s);
    m1 += __shfl_xor(m1, s);
    m2 += __shfl_xor(m2, s);
    x0 = fmaxf(x0, __shfl_xor(x0, s));
    x1 = fmaxf(x1, __shfl_xor(x1, s));
    x2 = fmaxf(x2, __shfl_xor(x2, s));
  }
  // broadcast group-0 (the true top-16 group) aggregates to all lanes
  const float inv = 1.0f / 16.0f;
  float ag[6];
  ag[0] = __shfl(m0, 0) * inv;
  ag[1] = __shfl(m1, 0) * inv;
  ag[2] = __shfl(m2, 0) * inv;
  ag[3] = __shfl(x0, 0);
  ag[4] = __shfl(x1, 0);
  ag[5] = __shfl(x2, 0);

  // ---- fused output: latent row + beta (reference-exact fma ordering) ----
  int oq = idxs[P];
  const float* xq = x + (size_t)oq * D;
  int o = lane < D ? lane : 0;
  float acc = 0.f;
#pragma unroll
  for (int d = 0; d < D; ++d) acc = fmaf(xq[d], lWo1[d * D + o], acc);
  float b2 = 0.f;
#pragma unroll
  for (int p = 0; p < 6; ++p) b2 = fmaf(ag[p], lWo2[p * D + o], b2);
  b2 = __fadd_rn(b2, lbo2[o]);
  float lat = __fadd_rn(acc, b2);
  if (lane < D) out[(size_t)N + (size_t)oq * D + lane] = lat;
  float z = 0.f;
#pragma unroll
  for (int o2 = 0; o2 < D; ++o2) z = fmaf(__shfl(lat, o2), lWb[o2], z);
  z = __fadd_rn(z, lbb[0]);
  if (lane == 0) {
    float beta = 1.0f / (1.0f + expf(-z));
    out[oq] = fminf(fmaxf(beta, 1e-6f), 1.0f - 1e-6f);
  }
}

// ---------------------------------------------------------------------------
extern "C" void kernel_launch(void* const* d_in, const int* in_sizes, int n_in,
                              void* d_out, int out_size, void* d_ws,
                              size_t ws_size, hipStream_t stream) {
  const float* x = (const float*)d_in[0];
  const float* Ws = (const float*)d_in[1];
  const float* bs = (const float*)d_in[2];
  const float* Wh = (const float*)d_in[3];
  const float* bh = (const float*)d_in[4];
  const float* Wo1 = (const float*)d_in[5];
  const float* Wo2 = (const float*)d_in[6];
  const float* bo2 = (const float*)d_in[7];
  const float* Wb = (const float*)d_in[8];
  const float* bb = (const float*)d_in[9];
  float* out = (float*)d_out;

  // ws (floats): s4[N*4] | h4[N*4] | s4s[N*4] | h4s[N*4] | idxs[N]i |
  // hist[32768]i | cnt2[32768]i | offs[32769]i   (~1.5 MB)
  float* ws = (float*)d_ws;
  float4* s4 = (float4*)ws;
  float4* h4 = (float4*)(ws + (size_t)N * 4);
  float4* s4s = (float4*)(ws + (size_t)N * 8);
  float4* h4s = (float4*)(ws + (size_t)N * 12);
  int* idxs = (int*)(ws + (size_t)N * 16);
  int* hist = idxs + N;
  int* cnt2 = hist + NCELL;
  int* offs = cnt2 + NCELL;

  zero_kernel<<<NCELL / 256, 256, 0, stream>>>(hist, cnt2);
  prep_kernel<<<N / 64, 64, 0, stream>>>(x, Ws, bs, Wh, bh, s4, h4, hist);
  scan_kernel<<<1, 1024, 0, stream>>>(hist, offs);
  scatter_kernel<<<N / 64, 64, 0, stream>>>(s4, h4, offs, cnt2, s4s, h4s,
                                            idxs);
  knn_kernel<<<N / 4, 256, 0, stream>>>(s4s, h4s, idxs, offs, x, Wo1, Wo2,
                                        bo2, Wb, bb, out);
}